// Round 1
// baseline (102.487 us; speedup 1.0000x reference)
//
#include <hip/hip_runtime.h>

#define COLS 8192
#define TPB  256

// Exact reproduction of the reference MXFP4 rounding:
// idx = searchsorted(MID, mag, side='right')  ==  #{mid : mid <= mag}
// GRID[idx] decomposes as a weighted sum of the 7 indicator bits:
//   0.5,0.5,0.5,0.5 (->2.0) then +1,+1,+2 gives 0,.5,1,1.5,2,3,4,6.
__device__ __forceinline__ float fp4_round(float v, float inv, float scale) {
    const float y   = v * inv;          // exact: inv is a power of two
    const float mag = fabsf(y);
    float g = (mag >= 0.25f) ? 0.5f : 0.0f;
    g += (mag >= 0.75f) ? 0.5f : 0.0f;
    g += (mag >= 1.25f) ? 0.5f : 0.0f;
    g += (mag >= 1.75f) ? 0.5f : 0.0f;
    g += (mag >= 2.5f)  ? 1.0f : 0.0f;
    g += (mag >= 3.5f)  ? 1.0f : 0.0f;
    g += (mag >= 5.0f)  ? 2.0f : 0.0f;
    return copysignf(g * scale, y);     // exact: g*scale has <=2 mantissa bits
}

__global__ __launch_bounds__(TPB) void permute_mxfp4_kernel(
    const float* __restrict__ x,
    const int*   __restrict__ perm,
    float*       __restrict__ out)
{
    __shared__ float row[COLS];                  // 32 KiB -> 5 blocks/CU
    const int    tid   = threadIdx.x;
    const size_t rbase = (size_t)blockIdx.x * COLS;
    const float* xrow  = x   + rbase;
    float*       orow  = out + rbase;

    // Stage the full row into LDS: coalesced 16B direct-to-LDS loads.
    // LDS layout is linear (wave-uniform base + lane*16) — the required
    // global_load_lds destination pattern.
#pragma unroll
    for (int i = 0; i < COLS / (4 * TPB); ++i) {
        const int f4 = i * TPB + tid;
        __builtin_amdgcn_global_load_lds(
            (const __attribute__((address_space(1))) unsigned int*)(xrow + 4 * f4),
            (__attribute__((address_space(3))) unsigned int*)(&row[4 * f4]),
            16, 0, 0);
    }
    __syncthreads();   // compiler emits s_waitcnt vmcnt(0) before the barrier

    // Each thread: 4 consecutive output columns per iteration.
    // Quant block = 32 columns = 8 consecutive lanes.
#pragma unroll
    for (int i = 0; i < COLS / (4 * TPB); ++i) {
        const int f4 = i * TPB + tid;
        const int c  = 4 * f4;
        const int4 p = *reinterpret_cast<const int4*>(perm + c);  // coalesced, L1/L2-hot

        const float v0 = row[p.x];   // random LDS gather, ~2-3x conflict cost
        const float v1 = row[p.y];
        const float v2 = row[p.z];
        const float v3 = row[p.w];

        float m = fmaxf(fmaxf(fabsf(v0), fabsf(v1)), fmaxf(fabsf(v2), fabsf(v3)));
        m = fmaxf(m, __shfl_xor(m, 1));   // reduce over the 8-lane quant group
        m = fmaxf(m, __shfl_xor(m, 2));
        m = fmaxf(m, __shfl_xor(m, 4));

        // scale = 2^(floor(log2(amax)) - 2); amax==0 (or denormal) -> 1.0
        const unsigned ebits = __float_as_uint(m) & 0x7F800000u;
        const float scale = ebits ? __uint_as_float(ebits) * 0.25f : 1.0f;
        const float inv   = 1.0f / scale;   // exact inverse of a power of two

        float4 q;
        q.x = fp4_round(v0, inv, scale);
        q.y = fp4_round(v1, inv, scale);
        q.z = fp4_round(v2, inv, scale);
        q.w = fp4_round(v3, inv, scale);
        *reinterpret_cast<float4*>(orow + c) = q;   // coalesced float4 store
    }
}

extern "C" void kernel_launch(void* const* d_in, const int* in_sizes, int n_in,
                              void* d_out, int out_size, void* d_ws, size_t ws_size,
                              hipStream_t stream) {
    const float* x    = (const float*)d_in[0];
    const int*   perm = (const int*)d_in[1];
    float*       out  = (float*)d_out;
    const int rows = out_size / COLS;   // 8192
    hipLaunchKernelGGL(permute_mxfp4_kernel, dim3(rows), dim3(TPB), 0, stream,
                       x, perm, out);
}

// Round 3
// 83.657 us; speedup vs baseline: 1.2251x; 1.2251x over previous
//
#include <hip/hip_runtime.h>

#define COLS 8192
#define TPB  512
#define ITERS (COLS / (4 * TPB))   // 4

typedef float  floatx4 __attribute__((ext_vector_type(4)));

// Exact reproduction of the reference MXFP4 rounding:
// idx = searchsorted(MID, mag, side='right')  ==  #{mid : mid <= mag}
// GRID[idx] decomposes as a weighted sum of the 7 indicator bits:
//   0.5,0.5,0.5,0.5 (->2.0) then +1,+1,+2 gives 0,.5,1,1.5,2,3,4,6.
__device__ __forceinline__ float fp4_round(float v, float inv, float scale) {
    const float y   = v * inv;          // exact: inv is a power of two
    const float mag = fabsf(y);
    float g = (mag >= 0.25f) ? 0.5f : 0.0f;
    g += (mag >= 0.75f) ? 0.5f : 0.0f;
    g += (mag >= 1.25f) ? 0.5f : 0.0f;
    g += (mag >= 1.75f) ? 0.5f : 0.0f;
    g += (mag >= 2.5f)  ? 1.0f : 0.0f;
    g += (mag >= 3.5f)  ? 1.0f : 0.0f;
    g += (mag >= 5.0f)  ? 2.0f : 0.0f;
    return copysignf(g * scale, y);     // exact: g*scale has <=2 mantissa bits
}

__global__ __launch_bounds__(TPB) void permute_mxfp4_kernel(
    const float* __restrict__ x,
    const int*   __restrict__ perm,
    float*       __restrict__ out)
{
    __shared__ float row[COLS];                  // 32 KiB -> 4 blocks/CU @512thr = 32 waves (100%)
    const int    tid   = threadIdx.x;
    const size_t rbase = (size_t)blockIdx.x * COLS;
    const float* xrow  = x   + rbase;
    float*       orow  = out + rbase;

    // Stage the full row into LDS: coalesced 16B direct-to-LDS loads.
    // LDS layout is linear (wave-uniform base + lane*16) — the required
    // global_load_lds destination pattern.
#pragma unroll
    for (int i = 0; i < ITERS; ++i) {
        const int f4 = i * TPB + tid;
        __builtin_amdgcn_global_load_lds(
            (const __attribute__((address_space(1))) unsigned int*)(xrow + 4 * f4),
            (__attribute__((address_space(3))) unsigned int*)(&row[4 * f4]),
            16, 0, 0);
    }

    // Preload this thread's permutation indices into registers while the
    // staging loads are in flight (drained together by the barrier's vmcnt(0)).
    int4 pr[ITERS];
#pragma unroll
    for (int i = 0; i < ITERS; ++i) {
        pr[i] = *reinterpret_cast<const int4*>(perm + 4 * (i * TPB + tid));
    }

    __syncthreads();   // compiler emits s_waitcnt vmcnt(0) before the barrier

    // Each thread: 4 consecutive output columns per iteration.
    // Quant block = 32 columns = 8 consecutive lanes.
#pragma unroll
    for (int i = 0; i < ITERS; ++i) {
        const int c  = 4 * (i * TPB + tid);
        const int4 p = pr[i];

        const float v0 = row[p.x];   // random LDS gather
        const float v1 = row[p.y];
        const float v2 = row[p.z];
        const float v3 = row[p.w];

        float m = fmaxf(fmaxf(fabsf(v0), fabsf(v1)), fmaxf(fabsf(v2), fabsf(v3)));
        m = fmaxf(m, __shfl_xor(m, 1));   // reduce over the 8-lane quant group
        m = fmaxf(m, __shfl_xor(m, 2));
        m = fmaxf(m, __shfl_xor(m, 4));

        // scale = 2^(floor(log2(amax)) - 2); amax==0 (or denormal) -> 1.0
        const unsigned ebits = __float_as_uint(m) & 0x7F800000u;
        const float scale = ebits ? __uint_as_float(ebits) * 0.25f : 1.0f;
        const float inv   = 1.0f / scale;   // exact inverse of a power of two

        floatx4 q;
        q.x = fp4_round(v0, inv, scale);
        q.y = fp4_round(v1, inv, scale);
        q.z = fp4_round(v2, inv, scale);
        q.w = fp4_round(v3, inv, scale);
        __builtin_nontemporal_store(q, reinterpret_cast<floatx4*>(orow + c));
    }
}

extern "C" void kernel_launch(void* const* d_in, const int* in_sizes, int n_in,
                              void* d_out, int out_size, void* d_ws, size_t ws_size,
                              hipStream_t stream) {
    const float* x    = (const float*)d_in[0];
    const int*   perm = (const int*)d_in[1];
    float*       out  = (float*)d_out;
    const int rows = out_size / COLS;   // 8192
    hipLaunchKernelGGL(permute_mxfp4_kernel, dim3(rows), dim3(TPB), 0, stream,
                       x, perm, out);
}